// Round 2
// baseline (177.013 us; speedup 1.0000x reference)
//
#include <hip/hip_runtime.h>

// AreaAttention (pykt), B=8,H=8,L=512,D=64, W=3, d_k=64, zero_pad=1, causal tril mask.
// Identities: window scores are running means of base scores s_j = (q.k_j)/8;
// output is sum_t coeff[t]*v[t] with coeff a local scatter of softmax probs;
// causal mask == (window end e <= q). Mask input (64 MB) never read.

#define LSEQ 512
#define DDIM 64
#define BQ 64
#define BK 64
#define NTH 256

__global__ __launch_bounds__(256, 2)
void area_attn_kernel(const float* __restrict__ qg,
                      const float* __restrict__ kg,
                      const float* __restrict__ vg,
                      float* __restrict__ outg) {
  const int bid = blockIdx.x;
  const int tid = threadIdx.x;

  // LDS (~70 KB -> 2 blocks/CU). KC doubles as K^T tile (GEMM phase) and
  // coeff^T tile (PV phase) -- K is dead once S is computed.
  __shared__ __align__(16) float Qs[64][68];   // Q^T [d][q], pre-scaled by 1/8
  __shared__ __align__(16) float KC[66 * 68];  // Ks(d,c)=KC[d*68+c]; Cs(cc,r)=KC[cc*68+r]
  __shared__ __align__(16) float Ss[64][68];   // [q][ec 0..63], cols 64..65 = s(t0-2), s(t0-1)
  __shared__ __align__(16) float Vs[66][64];   // rows 0..63 = v[t0+ec], 64..65 = v[t0-2],v[t0-1]
  __shared__ float scale_arr[64];
  __shared__ float l_arr[64];

  if (bid >= 512) {
    // ---- row0 path: q=0 with zero_pad -> all windows masked -> uniform
    // softmax over 1533 windows -> out = (1/1533) * sum_t c_t * v[t],
    // c_t = #windows containing t = {3,5,6,...,6,5,3}.
    const int bh = bid - 512;
    const float4* vb4 = (const float4*)(vg + (size_t)bh * LSEQ * DDIM);
    float4* red = (float4*)&Qs[0][0];
    const int d4 = tid & 15, rg = tid >> 4;
    float4 acc = make_float4(0.f, 0.f, 0.f, 0.f);
    for (int t = rg; t < LSEQ; t += 16) {
      float c = (t == 0 || t == LSEQ - 1) ? 3.f
              : (t == 1 || t == LSEQ - 2) ? 5.f : 6.f;
      float4 x = vb4[t * 16 + d4];
      acc.x += c * x.x; acc.y += c * x.y; acc.z += c * x.z; acc.w += c * x.w;
    }
    red[rg * 16 + d4] = acc;
    __syncthreads();
    if (rg == 0) {
      float4 s = make_float4(0.f, 0.f, 0.f, 0.f);
#pragma unroll
      for (int g = 0; g < 16; ++g) {
        float4 x = red[g * 16 + d4];
        s.x += x.x; s.y += x.y; s.z += x.z; s.w += x.w;
      }
      const float inv = 1.0f / 1533.0f;
      s.x *= inv; s.y *= inv; s.z *= inv; s.w *= inv;
      ((float4*)(outg + (size_t)bh * LSEQ * DDIM))[d4] = s;
    }
    return;
  }

  // ---- attention path. Balance remap: blocks i and i+256 (likely same CU at
  // 2 blocks/CU, round-robin over 8 XCDs) get qt and 7-qt -> 9 tile-units/CU.
  const int half = bid >> 8;  // 0 | 1
  const int qt = half ? (7 - (bid & 7)) : (bid & 7);
  const int bh = ((bid >> 3) & 31) + (half << 5);
  const int q0 = qt * BQ;

  const float* qb = qg + (size_t)bh * LSEQ * DDIM;
  const float* kb = kg + (size_t)bh * LSEQ * DDIM;
  const float* vb = vg + (size_t)bh * LSEQ * DDIM;

  // ---- stage Q^T (scaled by 1/sqrt(64)) ----
  {
    const float4* qa = (const float4*)(qb + q0 * DDIM);
#pragma unroll
    for (int it = 0; it < 4; ++it) {
      int f = tid + it * NTH;      // 0..1023 float4s
      int r = f >> 4;              // q row
      int c4 = f & 15;             // d/4
      float4 x = qa[f];
      int d0 = c4 * 4;
      Qs[d0 + 0][r] = x.x * 0.125f;
      Qs[d0 + 1][r] = x.y * 0.125f;
      Qs[d0 + 2][r] = x.z * 0.125f;
      Qs[d0 + 3][r] = x.w * 0.125f;
    }
  }

  const int ty = tid >> 4, tx = tid & 15;   // GEMM role: rows 4ty.., cols 4tx..
  const int r0 = ty * 4, c0 = tx * 4;
  const int pr = tid >> 2, ps = tid & 3;    // softmax role: row pr, sub ps
  const int ec0 = ps * 16;
  // wave w owns q-rows [16w,16w+16) in BOTH roles -> row state is wave-local.

  float Oa[4][4];
#pragma unroll
  for (int i = 0; i < 4; ++i)
#pragma unroll
    for (int j = 0; j < 4; ++j) Oa[i][j] = 0.f;
  float m_run = -3.0e38f, l_run = 0.f;

  const int ntiles = qt + 1;
  for (int kt = 0; kt < ntiles; ++kt) {
    const int t0 = kt * BK;

    // carry s-context (cols 62,63 of previous tile -> 64,65); barrier-safe:
    // producer (GEMM kt-1) is 2 barriers back, consumers are 2 barriers ahead.
    if (ps == 0) {
      if (kt == 0) { Ss[pr][64] = -1.0e30f; Ss[pr][65] = -1.0e30f; }
      else         { Ss[pr][64] = Ss[pr][62]; Ss[pr][65] = Ss[pr][63]; }
    }
    __syncthreads();  // B1: prev PV done reading KC(=Cs)/Vs before restaging

    // ---- stage K^T and V ----
    {
      const float4* ka = (const float4*)(kb + t0 * DDIM);
#pragma unroll
      for (int it = 0; it < 4; ++it) {
        int f = tid + it * NTH;
        int r = f >> 4;
        int c4 = f & 15;
        float4 x = ka[f];
        int d0 = c4 * 4;
        KC[(d0 + 0) * 68 + r] = x.x;
        KC[(d0 + 1) * 68 + r] = x.y;
        KC[(d0 + 2) * 68 + r] = x.z;
        KC[(d0 + 3) * 68 + r] = x.w;
      }
      const float4* va = (const float4*)(vb + t0 * DDIM);
#pragma unroll
      for (int it = 0; it < 4; ++it) {
        int f = tid + it * NTH;
        int r = f >> 4;
        int c4 = f & 15;
        ((float4*)Vs[r])[c4] = va[f];
      }
      if (tid < 32) {  // v context rows: v[t0-2], v[t0-1] (zeros on first tile)
        int rr = tid >> 4;
        int c4 = tid & 15;
        float4 x = make_float4(0.f, 0.f, 0.f, 0.f);
        if (kt > 0) x = ((const float4*)(vb + (size_t)(t0 - 2 + rr) * DDIM))[c4];
        ((float4*)Vs[64 + rr])[c4] = x;
      }
    }
    __syncthreads();  // B2

    // ---- S = (Q/8) K^T : 64x64x64 fp32, 4x4 micro-tile ----
    {
      float acc[4][4];
#pragma unroll
      for (int i = 0; i < 4; ++i)
#pragma unroll
        for (int j = 0; j < 4; ++j) acc[i][j] = 0.f;
#pragma unroll 8
      for (int d = 0; d < 64; ++d) {
        float4 qv = *(const float4*)&Qs[d][r0];
        float4 kv = *(const float4*)&KC[d * 68 + c0];
        float qr[4] = {qv.x, qv.y, qv.z, qv.w};
        float kr[4] = {kv.x, kv.y, kv.z, kv.w};
#pragma unroll
        for (int i = 0; i < 4; ++i)
#pragma unroll
          for (int j = 0; j < 4; ++j) acc[i][j] = fmaf(qr[i], kr[j], acc[i][j]);
      }
#pragma unroll
      for (int i = 0; i < 4; ++i) {
        float4 o = make_float4(acc[i][0], acc[i][1], acc[i][2], acc[i][3]);
        *(float4*)&Ss[r0 + i][c0] = o;
      }
    }
    __syncthreads();  // B3: KC free (all waves done with Ks) -> Cs writes legal

    // ---- online softmax over the 3 derived window scores per key ----
    {
      const int vmax = q0 + pr - t0;  // valid: ec <= vmax (>=0 always here)
      float pm1, pm2;                 // s at ec-1, ec-2 lead-ins
      if (ps == 0) { pm1 = Ss[pr][65]; pm2 = Ss[pr][64]; }
      else         { pm1 = Ss[pr][ec0 - 1]; pm2 = Ss[pr][ec0 - 2]; }

      // cache this thread's 16 S values once (4x ds_read_b128, reused twice)
      float sv[16];
      *(float4*)&sv[0]  = *(const float4*)&Ss[pr][ec0];
      *(float4*)&sv[4]  = *(const float4*)&Ss[pr][ec0 + 4];
      *(float4*)&sv[8]  = *(const float4*)&Ss[pr][ec0 + 8];
      *(float4*)&sv[12] = *(const float4*)&Ss[pr][ec0 + 12];

      float mloc = -3.0e38f;
      {
        float a1 = pm1, a2 = pm2;
#pragma unroll
        for (int k = 0; k < 16; ++k) {
          float s0 = sv[k];
          float sc2 = 0.5f * (a1 + s0);
          float sc3 = (1.0f / 3.0f) * (a2 + a1 + s0);
          float mm = fmaxf(s0, fmaxf(sc2, sc3));
          if (ec0 + k <= vmax) mloc = fmaxf(mloc, mm);
          a2 = a1; a1 = s0;
        }
      }
      mloc = fmaxf(mloc, __shfl_xor(mloc, 1));
      mloc = fmaxf(mloc, __shfl_xor(mloc, 2));
      const float m_new = fmaxf(m_run, mloc);
      const float alpha = __expf(m_run - m_new);
      m_run = m_new;
      if (ps == 0) scale_arr[pr] = alpha;
      l_run *= alpha;

      // pass 2: probs -> denom + local coeff scatter (each exp computed once).
      // window (w,e) contributes p_w(e) to coeff at t=e,e-1,..,e-w+1.
      float cf[18];  // cf[j] holds coeff for lt = 16*ps + j, lt = t - t0 + 2
#pragma unroll
      for (int k = 0; k < 18; ++k) cf[k] = 0.f;
      float ladd = 0.f;
      {
        float a1 = pm1, a2 = pm2;
#pragma unroll
        for (int k = 0; k < 16; ++k) {
          float s0 = sv[k];
          bool vld = (ec0 + k) <= vmax;
          float p1 = vld ? __expf(s0 - m_new) : 0.f;
          float p2 = vld ? __expf(0.5f * (a1 + s0) - m_new) : 0.f;
          float p3 = vld ? __expf((1.0f / 3.0f) * (a2 + a1 + s0) - m_new) : 0.f;
          ladd += p1 + p2 + p3;
          cf[k + 2] += p1 + p2 + p3;  // t = e
          cf[k + 1] += p2 + p3;       // t = e-1
          cf[k]     += p3;            // t = e-2
          a2 = a1; a1 = s0;
        }
      }
      ladd += __shfl_xor(ladd, 1);
      ladd += __shfl_xor(ladd, 2);
      l_run += ladd;
      if (ps == 0) l_arr[pr] = l_run;

      // Overlap resolution IN REGISTERS (race-free): lane ps's cf[16],cf[17]
      // (lt = 16ps+16,+17) belong to lane ps+1's cf[0],cf[1]. Shuffle them up;
      // then every LDS slot has exactly one writer, no read-modify-write.
      float up16 = __shfl_up(cf[16], 1, 4);
      float up17 = __shfl_up(cf[17], 1, 4);
      if (ps > 0) { cf[0] += up16; cf[1] += up17; }

      // write coeff^T: cc 0..63 <-> t0+cc (matches Vs rows), 64,65 <-> t0-2,t0-1
#pragma unroll
      for (int k = 0; k < 16; ++k) {
        int lt = ec0 + k;
        int cc = (lt >= 2) ? (lt - 2) : (64 + lt);
        KC[cc * 68 + pr] = cf[k];
      }
      if (ps == 3) {  // lt 64,65 -> cc 62,63, sole writer
        KC[62 * 68 + pr] = cf[16];
        KC[63 * 68 + pr] = cf[17];
      }
    }
    __syncthreads();  // B4: coeff^T/scale visible to PV role

    // ---- O = O*alpha + coeff^T x V (66 rows) ----
    {
      float al[4];
#pragma unroll
      for (int i = 0; i < 4; ++i) al[i] = scale_arr[r0 + i];
#pragma unroll
      for (int i = 0; i < 4; ++i)
#pragma unroll
        for (int j = 0; j < 4; ++j) Oa[i][j] *= al[i];
#pragma unroll 2
      for (int cc = 0; cc < 66; ++cc) {
        float4 cv = *(const float4*)&KC[cc * 68 + r0];
        float4 vv = *(const float4*)&Vs[cc][c0];
        float cr[4] = {cv.x, cv.y, cv.z, cv.w};
        float vr[4] = {vv.x, vv.y, vv.z, vv.w};
#pragma unroll
        for (int i = 0; i < 4; ++i)
#pragma unroll
          for (int j = 0; j < 4; ++j) Oa[i][j] = fmaf(cr[i], vr[j], Oa[i][j]);
      }
    }
  }

  // ---- epilogue: divide by softmax denom, store. Skip global row 0 (the
  // row0 blocks own it; avoids a cross-block writer race). ----
  {
#pragma unroll
    for (int i = 0; i < 4; ++i) {
      int gr = q0 + r0 + i;
      if (gr != 0) {
        float inv = 1.0f / l_arr[r0 + i];
        float4 o = make_float4(Oa[i][0] * inv, Oa[i][1] * inv,
                               Oa[i][2] * inv, Oa[i][3] * inv);
        *(float4*)(outg + (size_t)(bh * LSEQ + gr) * DDIM + c0) = o;
      }
    }
  }
}

extern "C" void kernel_launch(void* const* d_in, const int* in_sizes, int n_in,
                              void* d_out, int out_size, void* d_ws, size_t ws_size,
                              hipStream_t stream) {
  (void)in_sizes; (void)n_in; (void)d_ws; (void)ws_size; (void)out_size;
  const float* q = (const float*)d_in[0];
  const float* k = (const float*)d_in[1];
  const float* v = (const float*)d_in[2];
  float* out = (float*)d_out;

  // blocks 0..511: (bh, q-tile) attention; blocks 512..575: row0 fix per bh.
  dim3 grid(512 + 64);
  area_attn_kernel<<<grid, NTH, 0, stream>>>(q, k, v, out);
}

// Round 3
// 146.263 us; speedup vs baseline: 1.2102x; 1.2102x over previous
//
#include <hip/hip_runtime.h>

// AreaAttention (pykt), B=8,H=8,L=512,D=64, W=3, d_k=64, zero_pad=1, causal tril.
// Window scores are running means of base scores s_j=(q.k_j)/8; output is
// sum_t coeff[t]*v[t] with coeff a local scatter of softmax probs; causal
// mask == (window end <= q). Mask input (64 MB) never read.
// R3: both GEMMs on bf16 MFMA (16x16x32); wave-local phase layout -> 2
// barriers/tile; V pre-transposed to d_ws (bf16) by a helper kernel.

#define LSEQ 512
#define DDIM 64
#define BQ 64
#define BK 64
#define NTH 256

typedef __attribute__((ext_vector_type(8))) short bf8_t;   // 8 bf16 (4 VGPR)
typedef __attribute__((ext_vector_type(4))) float f32x4;

__device__ __forceinline__ unsigned short f2bf(float f) {  // RNE f32->bf16 bits
  union { float f; unsigned u; } v; v.f = f;
  unsigned u = v.u;
  unsigned r = u + 0x7fffu + ((u >> 16) & 1u);
  return (unsigned short)(r >> 16);
}
__device__ __forceinline__ float bf2f(unsigned short h) {
  union { unsigned u; float f; } v; v.u = ((unsigned)h) << 16; return v.f;
}
__device__ __forceinline__ unsigned pk2(float a, float b) {
  return (unsigned)f2bf(a) | ((unsigned)f2bf(b) << 16);
}
__device__ __forceinline__ float ex2(float x) {  // 1-instr exp2
  float r; asm("v_exp_f32 %0, %1" : "=v"(r) : "v"(x)); return r;
}
__device__ __forceinline__ bf8_t pack8(float4 a, float4 b, float s) {
  bf8_t r;
  r[0] = (short)f2bf(a.x * s); r[1] = (short)f2bf(a.y * s);
  r[2] = (short)f2bf(a.z * s); r[3] = (short)f2bf(a.w * s);
  r[4] = (short)f2bf(b.x * s); r[5] = (short)f2bf(b.y * s);
  r[6] = (short)f2bf(b.z * s); r[7] = (short)f2bf(b.w * s);
  return r;
}

// ---- pre-kernel: V^T[bh][d][t] bf16 into d_ws (coalesced reads; writes
// coalesce in L2 across iterations). grid 512: bh=bid>>3, oct=bid&7.
__global__ __launch_bounds__(256)
void vt_kernel(const float* __restrict__ vg, unsigned short* __restrict__ vt) {
  const int bh = blockIdx.x >> 3, oct = blockIdx.x & 7;
  const float* vb = vg + (size_t)bh * LSEQ * DDIM;
  unsigned short* vo = vt + (size_t)bh * DDIM * LSEQ;
#pragma unroll
  for (int it = 0; it < 4; ++it) {
    int item = threadIdx.x + it * 256;     // 1024 items: 64 d x 16 tq
    int d = item & 63, tq = item >> 6;
    int t = oct * 64 + tq * 4;
    ushort4 o;
    o.x = f2bf(vb[(t + 0) * DDIM + d]);
    o.y = f2bf(vb[(t + 1) * DDIM + d]);
    o.z = f2bf(vb[(t + 2) * DDIM + d]);
    o.w = f2bf(vb[(t + 3) * DDIM + d]);
    *(ushort4*)&vo[(size_t)d * LSEQ + t] = o;
  }
}

__global__ __launch_bounds__(256, 3)
void area_attn_kernel(const float* __restrict__ qg,
                      const float* __restrict__ kg,
                      const unsigned short* __restrict__ vtg,
                      float* __restrict__ outg) {
  const int bid = blockIdx.x;
  const int tid = threadIdx.x;

  // LDS ~45.5 KB -> 3 blocks/CU. Strides 72 (bf16) / 68 (f32) give uniform
  // bank spread on b128 fragment reads and conflict-free staging writes.
  __shared__ __align__(16) unsigned short Kbf[64 * 72];  // [key][d]
  __shared__ __align__(16) unsigned short Vt[64 * 72];   // [d][t], cols 64,65=ctx
  __shared__ __align__(16) unsigned short Ps[64 * 72];   // coeff [q][t], 64,65=ctx
  __shared__ __align__(16) float Ss[64][68];             // [q][e], 64,65=s ctx
  __shared__ float scale_arr[64];
  __shared__ float l_arr[64];

  if (bid >= 512) {
    // row0: q=0 with zero_pad -> all masked -> uniform over 1533 windows ->
    // out = (1/1533) * sum_t c_t v[t], c_t = {3,5,6,...,6,5,3}.
    const int bh = bid - 512;
    const unsigned short* vb = vtg + (size_t)bh * DDIM * LSEQ;  // V^T[d][t]
    float4* red = (float4*)&Ss[0][0];
    const int d4 = tid & 15, rg = tid >> 4;  // d-group, t-group
    float4 acc = make_float4(0.f, 0.f, 0.f, 0.f);
    // thread sums t = rg..511 step 16 for d = 4*d4..+3 (bf16 V^T reads)
    for (int t = rg; t < LSEQ; t += 16) {
      float c = (t == 0 || t == LSEQ - 1) ? 3.f
              : (t == 1 || t == LSEQ - 2) ? 5.f : 6.f;
      int d0 = d4 * 4;
      acc.x += c * bf2f(vb[(size_t)(d0 + 0) * LSEQ + t]);
      acc.y += c * bf2f(vb[(size_t)(d0 + 1) * LSEQ + t]);
      acc.z += c * bf2f(vb[(size_t)(d0 + 2) * LSEQ + t]);
      acc.w += c * bf2f(vb[(size_t)(d0 + 3) * LSEQ + t]);
    }
    red[rg * 16 + d4] = acc;
    __syncthreads();
    if (rg == 0) {
      float4 s = make_float4(0.f, 0.f, 0.f, 0.f);
#pragma unroll
      for (int g = 0; g < 16; ++g) {
        float4 x = red[g * 16 + d4];
        s.x += x.x; s.y += x.y; s.z += x.z; s.w += x.w;
      }
      const float inv = 1.0f / 1533.0f;
      s.x *= inv; s.y *= inv; s.z *= inv; s.w *= inv;
      ((float4*)(outg + (size_t)bh * LSEQ * DDIM))[d4] = s;
    }
    return;
  }

  // balance remap: pair qt with 7-qt across the two dispatch halves.
  const int half = bid >> 8;
  const int qt = half ? (7 - (bid & 7)) : (bid & 7);
  const int bh = ((bid >> 3) & 31) + (half << 5);
  const int q0 = qt * BQ;

  const float* qb = qg + (size_t)bh * LSEQ * DDIM;
  const float* kb = kg + (size_t)bh * LSEQ * DDIM;
  const unsigned short* vtb = vtg + (size_t)bh * DDIM * LSEQ;

  const int lane = tid & 63, w = tid >> 6;
  const int lc = lane & 15, lg = lane >> 4;   // frag col / k-group
  const int koff = lg * 8;
  const int pr = tid >> 2, ps = tid & 3;      // softmax: row pr, sub ps
  const int ec0 = ps * 16;
  const float L2E = 1.44269504088896341f;

  // ---- Q A-fragments in registers (scaled by 1/8; held for all tiles) ----
  bf8_t qa0, qa1;
  {
    const float* qrp = qb + (size_t)(q0 + 16 * w + lc) * DDIM;
    float4 xa = *(const float4*)(qrp + koff);
    float4 xb = *(const float4*)(qrp + koff + 4);
    qa0 = pack8(xa, xb, 0.125f);
    xa = *(const float4*)(qrp + 32 + koff);
    xb = *(const float4*)(qrp + 36 + koff);
    qa1 = pack8(xa, xb, 0.125f);
  }

  f32x4 oacc[4];
#pragma unroll
  for (int nt = 0; nt < 4; ++nt) oacc[nt] = (f32x4){0.f, 0.f, 0.f, 0.f};
  float m_run = -3.0e38f, l_run = 0.f;  // m in log2 units

  const int ntiles = qt + 1;
  for (int kt = 0; kt < ntiles; ++kt) {
    const int t0 = kt * BK;

    // s-context carry (raw scores), wave-local rows.
    if (ps == 0) {
      if (kt == 0) { Ss[pr][64] = -1.0e30f; Ss[pr][65] = -1.0e30f; }
      else         { Ss[pr][64] = Ss[pr][62]; Ss[pr][65] = Ss[pr][63]; }
    }
    __syncthreads();  // B1: all waves done reading Kbf/Vt of prev tile

    // ---- stage K (f32->bf16, row-major) and V^T (bf16 copy) ----
    {
      const float4* ka = (const float4*)(kb + (size_t)t0 * DDIM);
#pragma unroll
      for (int it = 0; it < 4; ++it) {
        int f = tid + it * NTH;
        int t = f >> 4, c4 = f & 15;
        float4 x = ka[t * 16 + c4];
        ushort4 o;
        o.x = f2bf(x.x); o.y = f2bf(x.y); o.z = f2bf(x.z); o.w = f2bf(x.w);
        *(ushort4*)&Kbf[t * 72 + c4 * 4] = o;
      }
#pragma unroll
      for (int it = 0; it < 4; ++it) {
        int f = tid + it * NTH;
        int d = f >> 4, tq = f & 15;
        ushort4 x = *(const ushort4*)&vtb[(size_t)d * LSEQ + t0 + tq * 4];
        *(ushort4*)&Vt[d * 72 + tq * 4] = x;
      }
      if (tid < 64) {  // v ctx cols: t0-2, t0-1 (zeros on first tile)
        unsigned x = 0;
        if (kt > 0) x = *(const unsigned*)&vtb[(size_t)tid * LSEQ + t0 - 2];
        *(unsigned*)&Vt[tid * 72 + 64] = x;
      }
    }
    __syncthreads();  // B2

    // ---- S = (Q/8) K^T via MFMA; write f32 to Ss (wave-local rows) ----
#pragma unroll
    for (int nt = 0; nt < 4; ++nt) {
      int key = nt * 16 + lc;
      bf8_t kb0 = *(const bf8_t*)&Kbf[key * 72 + koff];
      bf8_t kb1 = *(const bf8_t*)&Kbf[key * 72 + 32 + koff];
      f32x4 acc = (f32x4){0.f, 0.f, 0.f, 0.f};
      acc = __builtin_amdgcn_mfma_f32_16x16x32_bf16(qa0, kb0, acc, 0, 0, 0);
      acc = __builtin_amdgcn_mfma_f32_16x16x32_bf16(qa1, kb1, acc, 0, 0, 0);
#pragma unroll
      for (int r = 0; r < 4; ++r)
        Ss[16 * w + 4 * lg + r][nt * 16 + lc] = acc[r];
    }
    // no barrier: Ss rows / softmax rows / Ps rows / PV rows all wave-local

    // ---- online softmax over 3 derived window scores per key (log2 dom) ----
    {
      const int vmax = q0 + pr - t0;
      float pm1, pm2;
      if (ps == 0) { pm1 = Ss[pr][65] * L2E; pm2 = Ss[pr][64] * L2E; }
      else         { pm1 = Ss[pr][ec0 - 1] * L2E; pm2 = Ss[pr][ec0 - 2] * L2E; }

      float sv[16];
      *(float4*)&sv[0]  = *(const float4*)&Ss[pr][ec0];
      *(float4*)&sv[4]  = *(const float4*)&Ss[pr][ec0 + 4];
      *(float4*)&sv[8]  = *(const float4*)&Ss[pr][ec0 + 8];
      *(float4*)&sv[12] = *(const float4*)&Ss[pr][ec0 + 12];
#pragma unroll
      for (int k = 0; k < 16; ++k) sv[k] *= L2E;

      float mloc = -3.0e38f;
      {
        float a1 = pm1, a2 = pm2;
#pragma unroll
        for (int k = 0; k < 16; ++k) {
          float s0 = sv[k];
          float t = a1 + s0;
          float mm = fmaxf(s0, fmaxf(0.5f * t, (1.0f / 3.0f) * (a2 + t)));
          if (ec0 + k <= vmax) mloc = fmaxf(mloc, mm);
          a2 = a1; a1 = s0;
        }
      }
      mloc = fmaxf(mloc, __shfl_xor(mloc, 1));
      mloc = fmaxf(mloc, __shfl_xor(mloc, 2));
      const float m_new = fmaxf(m_run, mloc);
      const float alpha = ex2(m_run - m_new);
      m_run = m_new;
      if (ps == 0) scale_arr[pr] = alpha;
      l_run *= alpha;

      float cf[18];
#pragma unroll
      for (int k = 0; k < 18; ++k) cf[k] = 0.f;
      float ladd = 0.f;
      {
        float a1 = pm1, a2 = pm2;
#pragma unroll
        for (int k = 0; k < 16; ++k) {
          float s0 = sv[k];
          bool vld = (ec0 + k) <= vmax;
          float t = a1 + s0;
          float p1 = vld ? ex2(s0 - m_new) : 0.f;
          float p2 = vld ? ex2(0.5f * t - m_new) : 0.f;
          float p3 = vld ? ex2((1.0f / 3.0f) * (a2 + t) - m_new) : 0.f;
          float p23 = p2 + p3, p123 = p1 + p23;
          ladd += p123;
          cf[k + 2] += p123;   // t = e
          cf[k + 1] += p23;    // t = e-1
          cf[k]     += p3;     // t = e-2
          a2 = a1; a1 = s0;
        }
      }
      ladd += __shfl_xor(ladd, 1);
      ladd += __shfl_xor(ladd, 2);
      l_run += ladd;
      if (ps == 0) l_arr[pr] = l_run;

      // shuffle tail overlap into neighbor's head (register exchange, 1 writer
      // per LDS slot).
      float up16 = __shfl_up(cf[16], 1, 4);
      float up17 = __shfl_up(cf[17], 1, 4);
      if (ps > 0) { cf[0] += up16; cf[1] += up17; }

      // write coeff as packed bf16 pairs, row-major [q][t]; ctx at 64,65.
      const int base = pr * 72;
      if (ps == 0) {
        *(unsigned*)&Ps[base + 64] = pk2(cf[0], cf[1]);   // t0-2, t0-1
#pragma unroll
        for (int j = 0; j < 7; ++j)
          *(unsigned*)&Ps[base + 2 * j] = pk2(cf[2 + 2 * j], cf[3 + 2 * j]);
      } else {
        const int tcb = 16 * ps - 2;
#pragma unroll
        for (int j = 0; j < 8; ++j)
          *(unsigned*)&Ps[base + tcb + 2 * j] = pk2(cf[2 * j], cf[2 * j + 1]);
        if (ps == 3) *(unsigned*)&Ps[base + 62] = pk2(cf[16], cf[17]);
      }
    }
    // no barrier: PV reads wave-local rows of Ps / scale_arr

    // ---- O = O*alpha + coeff x V via MFMA (+ ctx VALU) ----
    {
      float al[4];
#pragma unroll
      for (int r = 0; r < 4; ++r) al[r] = scale_arr[16 * w + 4 * lg + r];
#pragma unroll
      for (int nt = 0; nt < 4; ++nt)
#pragma unroll
        for (int r = 0; r < 4; ++r) oacc[nt][r] *= al[r];

      bf8_t pa0 = *(const bf8_t*)&Ps[(16 * w + lc) * 72 + koff];
      bf8_t pa1 = *(const bf8_t*)&Ps[(16 * w + lc) * 72 + 32 + koff];
      float cm2[4], cm1[4];
#pragma unroll
      for (int r = 0; r < 4; ++r) {
        unsigned pc = *(const unsigned*)&Ps[(16 * w + 4 * lg + r) * 72 + 64];
        cm2[r] = bf2f((unsigned short)(pc & 0xffffu));
        cm1[r] = bf2f((unsigned short)(pc >> 16));
      }
#pragma unroll
      for (int nt = 0; nt < 4; ++nt) {
        int d = nt * 16 + lc;
        bf8_t vb0 = *(const bf8_t*)&Vt[d * 72 + koff];
        bf8_t vb1 = *(const bf8_t*)&Vt[d * 72 + 32 + koff];
        oacc[nt] = __builtin_amdgcn_mfma_f32_16x16x32_bf16(pa0, vb0, oacc[nt], 0, 0, 0);
        oacc[nt] = __builtin_amdgcn_mfma_f32_16x16x32_bf16(pa1, vb1, oacc[nt], 0, 0, 0);
        unsigned vc = *(const unsigned*)&Vt[d * 72 + 64];
        float vm2 = bf2f((unsigned short)(vc & 0xffffu));
        float vm1 = bf2f((unsigned short)(vc >> 16));
#pragma unroll
        for (int r = 0; r < 4; ++r)
          oacc[nt][r] += cm2[r] * vm2 + cm1[r] * vm1;
      }
    }
  }

  // ---- epilogue: divide by denom, store (skip global row 0) ----
  {
#pragma unroll
    for (int r = 0; r < 4; ++r) {
      int row = 16 * w + 4 * lg + r;
      int gr = q0 + row;
      if (gr != 0) {
        float inv = 1.0f / l_arr[row];
#pragma unroll
        for (int nt = 0; nt < 4; ++nt)
          outg[(size_t)(bh * LSEQ + gr) * DDIM + nt * 16 + lc] = oacc[nt][r] * inv;
      }
    }
  }
}

extern "C" void kernel_launch(void* const* d_in, const int* in_sizes, int n_in,
                              void* d_out, int out_size, void* d_ws, size_t ws_size,
                              hipStream_t stream) {
  (void)in_sizes; (void)n_in; (void)ws_size; (void)out_size;
  const float* q = (const float*)d_in[0];
  const float* k = (const float*)d_in[1];
  const float* v = (const float*)d_in[2];
  float* out = (float*)d_out;
  unsigned short* vt = (unsigned short*)d_ws;  // 64*64*512*2 = 4 MB

  vt_kernel<<<dim3(512), dim3(256), 0, stream>>>(v, vt);
  // blocks 0..511: (bh, q-tile); 512..575: row0 per bh.
  area_attn_kernel<<<dim3(512 + 64), dim3(256), 0, stream>>>(q, k, vt, out);
}